// Round 11
// baseline (74.442 us; speedup 1.0000x reference)
//
#include <hip/hip_runtime.h>

// SSIM loss, column-split 2-wave blocks (concurrency via independent blocks).
// x,y f32 [32,3,512,512] -> 2x2 pool (256x256) -> separable 11x11 Gaussian ->
// SSIM map 246x246 -> 1 - mean.
// R9 post-mortem: nothing saturated at 2 blocks/CU -> concurrency-starved.
// Block = (plane, 12-row strip), 128 threads = 2 waves, each wave 128 pooled
// cols (2 cols/lane). Ring of 11 pooled rows in registers (2 cols/lane ->
// 44 VGPR). Vertical 11-tap in regs; V-sums to block-shared double-buffered
// LDS row; one __syncthreads per step; horizontal 11-tap via float2 LDS reads
// (crosses the 128-col seam through LDS -> NO extra HBM halo vs R2).
// 2016 blocks ~ 7.9/CU -> ~16 waves/CU (2x R2's residency).

#define KS 11
#define H 12
#define ROWS (H + KS - 1)          // 22 pooled rows per strip
#define NSTRIP 21                  // 21*12 = 252 >= 246
#define NPLANE 96
#define NBLK (NPLANE * NSTRIP)     // 2016 blocks
#define NWAVE (NBLK * 2)           // 4032 partials
#define OUTD 246
#define BUFW 272                   // 256 + 16 zero-pad cols
#define C1V 1e-4f
#define C2V 9e-4f

__global__ __launch_bounds__(128) void ssim_strip(const float* __restrict__ x,
                                                  const float* __restrict__ y,
                                                  double* __restrict__ partial) {
    __shared__ float vbuf[2][5][BUFW];   // parity x plane x col = 10.88 KB
    const int tid = threadIdx.x;
    const int wv = tid >> 6, lane = tid & 63;
    const int gid = blockIdx.x;
    const int plane = gid / NSTRIP, strip = gid % NSTRIP;
    const int r0 = strip * H;
    const int colbase = wv * 128 + 2 * lane;          // this lane's pooled col pair
    const float* xp = x + (size_t)plane * 262144 + 2 * colbase;
    const float* yp = y + (size_t)plane * 262144 + 2 * colbase;

    float wt[KS];
    {
        float s = 0.f;
        #pragma unroll
        for (int i = 0; i < KS; ++i) {
            float d = (float)i - 5.f;
            wt[i] = expf(-d * d / 4.5f);   // 2*sigma^2 = 4.5
            s += wt[i];
        }
        float inv = 1.f / s;
        #pragma unroll
        for (int i = 0; i < KS; ++i) wt[i] *= inv;
    }

    // zero the 16 pad cols (both parities, 5 planes): reads past col 255 feed masked outputs
    for (int idx = tid; idx < 2 * 5 * 16; idx += 128) {
        int b = idx / 80, rest = idx % 80, p = rest / 16, c = rest % 16;
        vbuf[b][p][256 + c] = 0.f;
    }
    __syncthreads();

    // prime ring: pooled rows 0..9 (per lane: 1 float4 per image row per input)
    float rx[KS][2], ry[KS][2];
    #pragma unroll
    for (int i = 0; i < KS - 1; ++i) {
        int pr = r0 + i; pr = pr > 255 ? 255 : pr;
        const float* xr = xp + (size_t)(2 * pr) * 512;
        const float* yr = yp + (size_t)(2 * pr) * 512;
        float4 a0 = *(const float4*)xr, a1 = *(const float4*)(xr + 512);
        float4 b0 = *(const float4*)yr, b1 = *(const float4*)(yr + 512);
        rx[i][0] = (a0.x + a0.y + a1.x + a1.y) * 0.25f;
        rx[i][1] = (a0.z + a0.w + a1.z + a1.w) * 0.25f;
        ry[i][0] = (b0.x + b0.y + b1.x + b1.y) * 0.25f;
        ry[i][1] = (b0.z + b0.w + b1.z + b1.w) * 0.25f;
    }

    // raws for row 10 in flight
    float4 gx0, gx1, gy0, gy1;
    {
        int pr = r0 + KS - 1; pr = pr > 255 ? 255 : pr;
        const float* xr = xp + (size_t)(2 * pr) * 512;
        const float* yr = yp + (size_t)(2 * pr) * 512;
        gx0 = *(const float4*)xr; gx1 = *(const float4*)(xr + 512);
        gy0 = *(const float4*)yr; gy1 = *(const float4*)(yr + 512);
    }

    float local = 0.f;

    #pragma unroll 1
    for (int i = KS - 1; i < ROWS; ++i) {
        // consume raws (row i) -> push into ring slot KS-1
        rx[KS - 1][0] = (gx0.x + gx0.y + gx1.x + gx1.y) * 0.25f;
        rx[KS - 1][1] = (gx0.z + gx0.w + gx1.z + gx1.w) * 0.25f;
        ry[KS - 1][0] = (gy0.x + gy0.y + gy1.x + gy1.y) * 0.25f;
        ry[KS - 1][1] = (gy0.z + gy0.w + gy1.z + gy1.w) * 0.25f;

        // issue loads for row i+1 (consumed next iter; ~vertical+write cycles before barrier drain)
        if (i + 1 < ROWS) {
            int pr = r0 + i + 1; pr = pr > 255 ? 255 : pr;
            const float* xr = xp + (size_t)(2 * pr) * 512;
            const float* yr = yp + (size_t)(2 * pr) * 512;
            gx0 = *(const float4*)xr; gx1 = *(const float4*)(xr + 512);
            gy0 = *(const float4*)yr; gy1 = *(const float4*)(yr + 512);
        }

        // vertical 11-tap (register-only)
        float vm[5][2] = {{0,0},{0,0},{0,0},{0,0},{0,0}};
        #pragma unroll
        for (int k = 0; k < KS; ++k) {
            float wk = wt[k];
            #pragma unroll
            for (int c = 0; c < 2; ++c) {
                float xv = rx[k][c], yv = ry[k][c];
                vm[0][c] += wk * xv;       vm[1][c] += wk * yv;
                vm[2][c] += wk * xv * xv;  vm[3][c] += wk * yv * yv;
                vm[4][c] += wk * xv * yv;
            }
        }

        // rotate ring (static movs)
        #pragma unroll
        for (int k = 0; k < KS - 1; ++k) {
            #pragma unroll
            for (int c = 0; c < 2; ++c) { rx[k][c] = rx[k + 1][c]; ry[k][c] = ry[k + 1][c]; }
        }

        // stage V-sums to block-shared LDS (float2, 8B-aligned, ~2-way = free)
        const int par = i & 1;
        #pragma unroll
        for (int p = 0; p < 5; ++p)
            *(float2*)&vbuf[par][p][colbase] = make_float2(vm[p][0], vm[p][1]);

        __syncthreads();   // V-sums (incl. seam cols from the other wave) visible

        // horizontal 11-tap: window cols colbase..colbase+12 via 7 float2 reads
        const int ro = r0 + i - (KS - 1);
        float hp[5][2];
        #pragma unroll
        for (int p = 0; p < 5; ++p) {
            const float* bp = &vbuf[par][p][colbase];
            float w[14];
            #pragma unroll
            for (int j = 0; j < 7; ++j) {
                float2 t = *(const float2*)(bp + 2 * j);
                w[2 * j] = t.x; w[2 * j + 1] = t.y;
            }
            #pragma unroll
            for (int c = 0; c < 2; ++c) {
                float a = 0.f;
                #pragma unroll
                for (int j = 0; j < KS; ++j) a += wt[j] * w[c + j];
                hp[p][c] = a;
            }
        }

        if (ro < OUTD) {
            #pragma unroll
            for (int c = 0; c < 2; ++c) {
                int oc = colbase + c;
                float mx = hp[0][c], my = hp[1][c];
                float mxx = mx * mx, myy = my * my, mxy = mx * my;
                float sxx = hp[2][c] - mxx, syy = hp[3][c] - myy, sxy = hp[4][c] - mxy;
                float num = (2.f * mxy + C1V) * (2.f * sxy + C2V);
                float den = (mxx + myy + C1V) * (sxx + syy + C2V);
                float ss = num / den;
                local += (oc < OUTD) ? ss : 0.f;
            }
        }
    }

    // wave reduce, one partial per wave
    #pragma unroll
    for (int off = 32; off > 0; off >>= 1)
        local += __shfl_down(local, off, 64);
    if (lane == 0) partial[gid * 2 + wv] = (double)local;
}

__global__ __launch_bounds__(256) void ssim_finalize(const double* __restrict__ partial,
                                                     float* __restrict__ out) {
    const int tid = threadIdx.x;
    double s = 0.0;
    for (int i = tid; i < NWAVE; i += 256) s += partial[i];
    #pragma unroll
    for (int off = 32; off > 0; off >>= 1)
        s += __shfl_down(s, off, 64);
    __shared__ double sd[4];
    if ((tid & 63) == 0) sd[tid >> 6] = s;
    __syncthreads();
    if (tid == 0) {
        double total = sd[0] + sd[1] + sd[2] + sd[3];
        const double n = (double)NPLANE * OUTD * OUTD;   // 5,809,536
        out[0] = (float)(1.0 - total / n);
    }
}

extern "C" void kernel_launch(void* const* d_in, const int* in_sizes, int n_in,
                              void* d_out, int out_size, void* d_ws, size_t ws_size,
                              hipStream_t stream) {
    const float* x = (const float*)d_in[0];
    const float* y = (const float*)d_in[1];
    float* out = (float*)d_out;
    double* partial = (double*)d_ws;   // NWAVE * 8 = 32.25 KiB

    ssim_strip<<<NBLK, 128, 0, stream>>>(x, y, partial);
    ssim_finalize<<<1, 256, 0, stream>>>(partial, out);
}